// Round 9
// baseline (3148.143 us; speedup 1.0000x reference)
//
#include <hip/hip_runtime.h>
#include <hip/hip_bf16.h>
#include <math.h>

// Problem constants
#define BB 16
#define TT 512
#define FF 40
#define CC 256
#define HH 256
#define GG 768   // 3*H
#define NB 16

typedef _Float16 f16;
typedef __attribute__((ext_vector_type(8))) _Float16 f16x8;
typedef __attribute__((ext_vector_type(4))) _Float16 f16x4;
typedef __attribute__((ext_vector_type(4))) float f32x4;

// Workspace layout (float offsets). All activations f16 now.
#define O_OUT1 0u                       // out1h [b][h][w8][ci] f16 (33.5 MB); gi2 aliases after conv2
#define O_GI   0u                       // gi2 [s][g][b] f16, 12 MB
#define O_OUT2 16777216u                // out2h [b][h][w2][ci] f16 (8.4 MB)
#define O_OUT3 20971520u                // out3h [bt][c] f16 (4.2 MB); hsave aliases after gi_mfma
#define O_W2P  23068672u                // packed fp16 conv2 weights, 1638400 halves
#define O_W3P  24707072u                // packed fp16 conv3 weights, 983040 halves (+ wclsp 4096 halves)
#define O_WIHP 26345472u                // packed fp16 wih, 196608 halves
#define O_WHHP 26443776u                // packed fp16 whh, 196608 halves (dedicated, packed upfront)
// total 26542080 floats = 106.2 MB

__device__ __forceinline__ float sigm_fast(float x) {
    return __builtin_amdgcn_rcpf(1.f + __expf(-x));
}
__device__ __forceinline__ float tanh_fast(float x) {
    return 1.f - 2.f * __builtin_amdgcn_rcpf(1.f + __expf(2.f * x));
}

// ---------------- merged weight prep ----------------
// 768x256 matrix -> B-fragment order (shared by wih and whh).
__device__ __forceinline__ void pack768(const float* __restrict__ src, f16* __restrict__ dst, int e) {
    int lane = e & 63;
    int r1 = e >> 6;                            // 0..383
    int tile = r1 % 48, kf = r1 / 48;
    int g = tile * 16 + (lane & 15);
    int k0 = kf * 32 + (lane >> 4) * 8;
    f16x8 v;
#pragma unroll
    for (int j = 0; j < 8; ++j)
        v[j] = (f16)src[(size_t)g * HH + k0 + j];
    *(f16x8*)(dst + (size_t)e * 8) = v;
}

__global__ __launch_bounds__(256) void pack_all_kernel(
    const float* __restrict__ w2, const float* __restrict__ w3,
    const float* __restrict__ wih, const float* __restrict__ whh,
    const float* __restrict__ wcls,
    f16* __restrict__ w2p, f16* __restrict__ w3p, f16* __restrict__ wihp,
    f16* __restrict__ whhp, f16* __restrict__ wclsp) {
    int blk = blockIdx.x;
    int tid = threadIdx.x;
    if (blk < 800) {                            // conv2 weights (25 taps)
        int e = blk * 256 + tid;
        int lane = e & 63;
        int r1 = e >> 6;
        int ntile = r1 & 15;
        int r2 = r1 >> 4;
        int cs4 = r2 & 3;
        int r3 = r2 >> 2;
        int cs = r3 & 1;
        int tap = r3 >> 1;
        int co = ntile * 16 + (lane & 15);
        int ci0 = cs * 128 + cs4 * 32 + (lane >> 4) * 8;
        f16x8 v;
#pragma unroll
        for (int j = 0; j < 8; ++j)
            v[j] = (f16)w2[(size_t)co * 6400 + (ci0 + j) * 25 + tap];
        *(f16x8*)(w2p + (size_t)e * 8) = v;
    } else if (blk < 1280) {                    // conv3 weights (15 taps, kw in {1,2,3})
        int e = (blk - 800) * 256 + tid;
        int lane = e & 63;
        int r1 = e >> 6;
        int ntile = r1 & 15;
        int r2 = r1 >> 4;
        int cs4 = r2 & 3;
        int r3 = r2 >> 2;
        int cs = r3 & 1;
        int tap = r3 >> 1;
        int kh = tap / 3, kw = tap % 3 + 1;
        int co = ntile * 16 + (lane & 15);
        int ci0 = cs * 128 + cs4 * 32 + (lane >> 4) * 8;
        f16x8 v;
#pragma unroll
        for (int j = 0; j < 8; ++j)
            v[j] = (f16)w3[(size_t)co * 6400 + (ci0 + j) * 25 + kh * 5 + kw];
        *(f16x8*)(w3p + (size_t)e * 8) = v;
    } else if (blk < 1376) {
        pack768(wih, wihp, (blk - 1280) * 256 + tid);
    } else if (blk < 1472) {
        pack768(whh, whhp, (blk - 1376) * 256 + tid);
    } else {                                    // wcls: 512 entries
#pragma unroll
        for (int i = 0; i < 2; ++i) {
            int e = tid + i * 256;
            int lane = e & 63, kf = e >> 6;
            int nb = lane & 15;
            int c0 = kf * 32 + (lane >> 4) * 8;
            f16x8 v;
#pragma unroll
            for (int j = 0; j < 8; ++j)
                v[j] = (f16)wcls[nb * HH + c0 + j];
            *(f16x8*)(wclsp + (size_t)e * 8) = v;
        }
    }
}

// ---------------- conv block 1 (fp32 compute, f16 output [b][h][w][ci]) ----------------
__global__ __launch_bounds__(256) void conv1_kernel(
    const float* __restrict__ x, const float* __restrict__ w1,
    const float* __restrict__ b1, const float* __restrict__ g1,
    const float* __restrict__ bt1, const float* __restrict__ m1,
    const float* __restrict__ v1, f16* __restrict__ out1h) {
    int h = blockIdx.x;          // 512
    int b = blockIdx.y;          // 16
    int c = threadIdx.x;         // 256
    __shared__ float xs[5][44];
    int t = threadIdx.x;
    if (t < 220) {
        int rr = t / 44, cc = t % 44;
        int hh = h + rr - 2, ww = cc - 2;
        float v = 0.f;
        if (hh >= 0 && hh < TT && ww >= 0 && ww < FF) v = x[(b * TT + hh) * FF + ww];
        xs[rr][cc] = v;
    }
    __syncthreads();
    float wr[25];
#pragma unroll
    for (int i = 0; i < 25; ++i) wr[i] = w1[c * 25 + i];
    float sc = g1[c] * rsqrtf(v1[c] + 1e-5f);
    float sh = (b1[c] - m1[c]) * sc + bt1[c];
    float conv[40];
#pragma unroll
    for (int w = 0; w < 40; ++w) conv[w] = 0.f;
#pragma unroll
    for (int kh = 0; kh < 5; ++kh) {
        float rr[44];
#pragma unroll
        for (int i = 0; i < 44; ++i) rr[i] = xs[kh][i];
#pragma unroll
        for (int kw = 0; kw < 5; ++kw) {
            float wv = wr[kh * 5 + kw];
#pragma unroll
            for (int w = 0; w < 40; ++w) conv[w] += rr[w + kw] * wv;
        }
    }
    f16* op = out1h + ((size_t)(b * TT + h) * 8) * CC + c;
#pragma unroll
    for (int j = 0; j < 8; ++j) {
        float m = 0.f;   // relu folded into pool
#pragma unroll
        for (int p = 0; p < 5; ++p) m = fmaxf(m, conv[j * 5 + p] * sc + sh);
        op[j * CC] = (f16)m;
    }
}

// ---------------- conv block 2: fp16 MFMA implicit GEMM (f16 in/out) ----------------
__global__ __launch_bounds__(256) void conv2_mfma_kernel(
    const f16* __restrict__ in, const f16* __restrict__ w2p,
    const float* __restrict__ b2, const float* __restrict__ g2,
    const float* __restrict__ bt2, const float* __restrict__ m2,
    const float* __restrict__ v2, f16* __restrict__ out2h) {
    int htile = blockIdx.x;                 // 64
    int b = blockIdx.y;                     // 16
    int h0 = htile * 8;
    int t = threadIdx.x;
    int lane = t & 63, wid = t >> 6;
    int m16 = lane & 15, kq = lane >> 4;

    __shared__ f16 lds_a[12 * 12 * 136];    // 39168 B

#pragma unroll
    for (int i = 0; i < 39; ++i) {
        int idx = t + i * 256;
        if (idx < 9792) ((unsigned*)lds_a)[idx] = 0u;
    }
    __syncthreads();

    f32x4 acc[4][4];
#pragma unroll
    for (int mf = 0; mf < 4; ++mf)
#pragma unroll
        for (int nf = 0; nf < 4; ++nf) acc[mf][nf] = (f32x4)(0.f);

    for (int cs = 0; cs < 2; ++cs) {
        if (cs) __syncthreads();
        // stage: 12 rows x 8 w x 16 ci8-chunks = 1536 tasks of one 16-B copy
#pragma unroll
        for (int i = 0; i < 6; ++i) {
            int q = t + i * 256;
            int row = q >> 7, rem = q & 127;
            int w = rem >> 4, ci8 = (rem & 15) * 8;
            int hp = h0 - 2 + row;
            f16x8 v = (f16x8)((f16)0.f);
            if (hp >= 0 && hp < TT)
                v = *(const f16x8*)&in[((size_t)(b * TT + hp) * 8 + w) * CC + cs * 128 + ci8];
            *(f16x8*)&lds_a[row * 1632 + (w + 2) * 136 + ci8] = v;
        }
        __syncthreads();
        for (int kh = 0; kh < 5; ++kh) {
#pragma unroll
            for (int kw = 0; kw < 5; ++kw) {
                int tap = kh * 5 + kw;
#pragma unroll
                for (int cs4 = 0; cs4 < 4; ++cs4) {
                    f16x8 af[4];
#pragma unroll
                    for (int mf = 0; mf < 4; ++mf) {
                        int m = mf * 16 + m16;
                        int row = (m >> 3) + kh;
                        int wp = (m & 7) + kw;
                        af[mf] = *(const f16x8*)&lds_a[row * 1632 + wp * 136 + cs4 * 32 + kq * 8];
                    }
                    const f16x8* bp = (const f16x8*)w2p
                        + ((size_t)(((tap * 2 + cs) * 4 + cs4) * 16 + wid * 4) * 64 + lane);
#pragma unroll
                    for (int nf = 0; nf < 4; ++nf) {
                        f16x8 bf = bp[nf * 64];
#pragma unroll
                        for (int mf = 0; mf < 4; ++mf)
                            acc[mf][nf] = __builtin_amdgcn_mfma_f32_16x16x32_f16(af[mf], bf, acc[mf][nf], 0, 0, 0);
                    }
                }
            }
        }
    }

#pragma unroll
    for (int nf = 0; nf < 4; ++nf) {
        int co = wid * 64 + nf * 16 + m16;
        float sc = g2[co] * rsqrtf(v2[co] + 1e-5f);
        float sh = (b2[co] - m2[co]) * sc + bt2[co];
#pragma unroll
        for (int mf = 0; mf < 4; ++mf) {
            f32x4 v = acc[mf][nf];
            float p = 0.f;
            p = fmaxf(p, v[0] * sc + sh);
            p = fmaxf(p, v[1] * sc + sh);
            p = fmaxf(p, v[2] * sc + sh);
            p = fmaxf(p, v[3] * sc + sh);
            int dh = mf * 2 + (kq >> 1);
            int wout = kq & 1;
            out2h[((size_t)(b * TT + h0 + dh) * 2 + wout) * CC + co] = (f16)p;
        }
    }
}

// ---------------- conv block 3: fp16 MFMA implicit GEMM (f16 in/out) ----------------
__global__ __launch_bounds__(256) void conv3_mfma_kernel(
    const f16* __restrict__ in, const f16* __restrict__ w3p,
    const float* __restrict__ b3, const float* __restrict__ g3,
    const float* __restrict__ bt3, const float* __restrict__ m3,
    const float* __restrict__ v3, f16* __restrict__ out3h) {
    int htile = blockIdx.x;                 // 32
    int b = blockIdx.y;                     // 16
    int h0 = htile * 16;
    int t = threadIdx.x;
    int lane = t & 63, wid = t >> 6;
    int m16 = lane & 15, quad = lane >> 4;
    int rb = m16 >> 1, wv = m16 & 1;

    __shared__ f16 lds_a[20 * 6 * 136];     // 32640 B

    for (int i = t; i < 8160; i += 256) ((unsigned*)lds_a)[i] = 0u;
    __syncthreads();

    f32x4 acc[2][4];
#pragma unroll
    for (int mf = 0; mf < 2; ++mf)
#pragma unroll
        for (int nf = 0; nf < 4; ++nf) acc[mf][nf] = (f32x4)(0.f);

    for (int cs = 0; cs < 2; ++cs) {
        if (cs) __syncthreads();
        // stage: 20 rows x 2 w x 16 ci8-chunks = 640 tasks of one 16-B copy
#pragma unroll
        for (int i = 0; i < 3; ++i) {
            int q = t + i * 256;
            if (q < 640) {
                int row = q >> 5, rem = q & 31;
                int w = rem >> 4, ci8 = (rem & 15) * 8;
                int hp = h0 - 2 + row;
                f16x8 v = (f16x8)((f16)0.f);
                if (hp >= 0 && hp < TT)
                    v = *(const f16x8*)&in[((size_t)(b * TT + hp) * 2 + w) * CC + cs * 128 + ci8];
                *(f16x8*)&lds_a[row * 816 + (w + 2) * 136 + ci8] = v;
            }
        }
        __syncthreads();
        for (int kh = 0; kh < 5; ++kh) {
#pragma unroll
            for (int kw3 = 0; kw3 < 3; ++kw3) {
                int tap = kh * 3 + kw3;
#pragma unroll
                for (int cs4 = 0; cs4 < 4; ++cs4) {
                    f16x8 af[2];
#pragma unroll
                    for (int mf = 0; mf < 2; ++mf) {
                        int row = mf * 8 + rb + kh;
                        int wp = wv + kw3 + 1;
                        af[mf] = *(const f16x8*)&lds_a[row * 816 + wp * 136 + cs4 * 32 + quad * 8];
                    }
                    const f16x8* bp = (const f16x8*)w3p
                        + ((size_t)(((tap * 2 + cs) * 4 + cs4) * 16 + wid * 4) * 64 + lane);
#pragma unroll
                    for (int nf = 0; nf < 4; ++nf) {
                        f16x8 bf = bp[nf * 64];
#pragma unroll
                        for (int mf = 0; mf < 2; ++mf)
                            acc[mf][nf] = __builtin_amdgcn_mfma_f32_16x16x32_f16(af[mf], bf, acc[mf][nf], 0, 0, 0);
                    }
                }
            }
        }
    }

#pragma unroll
    for (int nf = 0; nf < 4; ++nf) {
        int co = wid * 64 + nf * 16 + m16;
        float sc = g3[co] * rsqrtf(v3[co] + 1e-5f);
        float sh = (b3[co] - m3[co]) * sc + bt3[co];
#pragma unroll
        for (int mf = 0; mf < 2; ++mf) {
            f32x4 v = acc[mf][nf];
            float p0 = fmaxf(0.f, fmaxf(v[0], v[1]) * sc + sh);
            p0 = fmaxf(p0, fmaxf(0.f, fminf(v[0], v[1]) * sc + sh));
            float p1 = fmaxf(0.f, fmaxf(v[2], v[3]) * sc + sh);
            p1 = fmaxf(p1, fmaxf(0.f, fminf(v[2], v[3]) * sc + sh));
            int h = h0 + mf * 8 + quad * 2;
            out3h[((size_t)(b * TT + h)) * CC + co] = (f16)p0;
            out3h[((size_t)(b * TT + h + 1)) * CC + co] = (f16)p1;
        }
    }
}

// ---------------- gi GEMM via MFMA -> gi2 [s][g][b] fp16 ----------------
__global__ __launch_bounds__(256) void gi_mfma_kernel(
    const f16* __restrict__ feats, const f16* __restrict__ wihp,
    const float* __restrict__ bih, f16* __restrict__ gi2) {
    int bt0 = blockIdx.x * 16;
    int b0 = bt0 >> 9, s0 = bt0 & 511;
    int t = threadIdx.x;
    int w = t >> 6, lane = t & 63;
    int m16 = lane & 15, quad = lane >> 4;
    f32x4 acc[12];
#pragma unroll
    for (int i = 0; i < 12; ++i) acc[i] = (f32x4)(0.f);
#pragma unroll
    for (int kf = 0; kf < 8; ++kf) {
        f16x8 af = *(const f16x8*)&feats[((size_t)(bt0 + m16)) * CC + kf * 32 + quad * 8];
#pragma unroll
        for (int nt = 0; nt < 12; ++nt) {
            f16x8 bf = ((const f16x8*)wihp)[(size_t)(kf * 48 + w * 12 + nt) * 64 + lane];
            acc[nt] = __builtin_amdgcn_mfma_f32_16x16x32_f16(af, bf, acc[nt], 0, 0, 0);
        }
    }
#pragma unroll
    for (int nt = 0; nt < 12; ++nt) {
        int g = (w * 12 + nt) * 16 + m16;
        float bv = bih[g];
#pragma unroll
        for (int r = 0; r < 4; ++r) {
            int s = s0 + quad * 4 + r;
            gi2[((size_t)s * GG + g) * 16 + b0] = (f16)(acc[nt][r] + bv);
        }
    }
}

// ---------------- GRU scan: 16 waves, pinned weights, 1 barrier/step ----------------
// Changes vs R8: gi prefetched one step ahead (regs); MFMA split into 6 independent
// 4-deep chains; hsave emitted as a cooperative coalesced LDS->global copy of the
// previous step's hA parity (replaces 4 scalar stores/thread/step).
__global__ __launch_bounds__(1024) void gru_mfma_kernel(
    const f16* __restrict__ gi2, const f16* __restrict__ whhp,
    const float* __restrict__ bhh, f16* __restrict__ hsave) {
    int t = threadIdx.x;
    int w = t >> 6, lane = t & 63;        // w = 0..15
    int n16 = lane & 15, quad = lane >> 4;
    __shared__ f16 hA[2][16 * 264];       // [parity][b][k], pad 8 halves

    for (int i = t; i < 2 * 16 * 264; i += 1024) ((f16*)hA)[i] = (f16)0.f;

    // preload + PIN 3 weight tiles (96 regs, lands in unified VGPR/AGPR file)
    f16x8 wfrag[8][3];
#pragma unroll
    for (int kf = 0; kf < 8; ++kf)
#pragma unroll
        for (int g = 0; g < 3; ++g)
            wfrag[kf][g] = ((const f16x8*)whhp)[(size_t)(kf * 48 + g * 16 + w) * 64 + lane];
#pragma unroll
    for (int kf = 0; kf < 8; ++kf)
#pragma unroll
        for (int g = 0; g < 3; ++g)
            asm volatile("" : "+v"(wfrag[kf][g]));   // opaque: cannot be re-loaded

    int c = w * 16 + n16;
    float bh0 = bhh[c], bh1 = bhh[HH + c], bh2 = bhh[2 * HH + c];
    float hold[4] = {0.f, 0.f, 0.f, 0.f};
    // hsave-copy task (threads 0..511): b = t>>5, c0 = (t&31)*8
    int cb_b = t >> 5, cb_c0 = (t & 31) * 8;
    __syncthreads();

    // prefetch gi for step 0
    f16x4 gic[3];
#pragma unroll
    for (int j = 0; j < 3; ++j)
        gic[j] = *(const f16x4*)&gi2[((size_t)0 * GG + c + j * HH) * 16 + quad * 4];

    for (int s = 0; s < TT; ++s) {
        // prefetch gi for step s+1 (consumed after the barrier; full step of slack)
        f16x4 gin[3];
        if (s + 1 < TT) {
#pragma unroll
            for (int j = 0; j < 3; ++j)
                gin[j] = *(const f16x4*)&gi2[((size_t)(s + 1) * GG + c + j * HH) * 16 + quad * 4];
        }

        // coalesced deferred hsave copy for step s-1: hA[s&1] holds h(s-1)
        if (s > 0 && t < 512) {
            f16x8 hv = *(const f16x8*)&hA[s & 1][cb_b * 264 + cb_c0];
            *(f16x8*)&hsave[((size_t)(s - 1) * 16 + cb_b) * 256 + cb_c0] = hv;
        }

        // gate GEMM: 6 independent 4-deep MFMA chains
        f32x4 accA[3], accB[3];
#pragma unroll
        for (int g = 0; g < 3; ++g) { accA[g] = (f32x4)(0.f); accB[g] = (f32x4)(0.f); }
#pragma unroll
        for (int kf = 0; kf < 4; ++kf) {
            f16x8 afA = *(const f16x8*)&hA[s & 1][n16 * 264 + kf * 32 + quad * 8];
            f16x8 afB = *(const f16x8*)&hA[s & 1][n16 * 264 + (kf + 4) * 32 + quad * 8];
#pragma unroll
            for (int g = 0; g < 3; ++g) {
                accA[g] = __builtin_amdgcn_mfma_f32_16x16x32_f16(afA, wfrag[kf][g], accA[g], 0, 0, 0);
                accB[g] = __builtin_amdgcn_mfma_f32_16x16x32_f16(afB, wfrag[kf + 4][g], accB[g], 0, 0, 0);
            }
        }

#pragma unroll
        for (int r = 0; r < 4; ++r) {
            float a0 = accA[0][r] + accB[0][r];
            float a1 = accA[1][r] + accB[1][r];
            float a2 = accA[2][r] + accB[2][r];
            float rr = sigm_fast((float)gic[0][r] + bh0 + a0);
            float zz = sigm_fast((float)gic[1][r] + bh1 + a1);
            float nn = tanh_fast((float)gic[2][r] + rr * (bh2 + a2));
            hold[r] = nn + zz * (hold[r] - nn);
        }

        int nb = (s + 1) & 1;
#pragma unroll
        for (int r = 0; r < 4; ++r)
            hA[nb][(quad * 4 + r) * 264 + c] = (f16)hold[r];
        __syncthreads();                  // writes(s) visible; reads(s) + prefetches drained
#pragma unroll
        for (int j = 0; j < 3; ++j) gic[j] = gin[j];
    }
    // final hsave copy (step TT-1): h(TT-1) lives in hA[TT&1] = hA[0]
    if (t < 512) {
        f16x8 hv = *(const f16x8*)&hA[0][cb_b * 264 + cb_c0];
        *(f16x8*)&hsave[((size_t)(TT - 1) * 16 + cb_b) * 256 + cb_c0] = hv;
    }
}

// ---------------- classifier: [8192 bt x 256] @ [256 x 16], MFMA ----------------
__global__ __launch_bounds__(256) void cls_kernel(
    const f16* __restrict__ hsave, const f16* __restrict__ wclsp,
    const float* __restrict__ bcls, float* __restrict__ out) {
    int s = blockIdx.x * 4 + (threadIdx.x >> 6);   // grid 128, one s per wave
    int lane = threadIdx.x & 63;
    int n16 = lane & 15, quad = lane >> 4;
    f32x4 ac = (f32x4)(0.f);
#pragma unroll
    for (int kf = 0; kf < 8; ++kf) {
        f16x8 af = *(const f16x8*)&hsave[((size_t)s * 16 + n16) * 256 + kf * 32 + quad * 8];
        f16x8 bf = ((const f16x8*)wclsp)[kf * 64 + lane];
        ac = __builtin_amdgcn_mfma_f32_16x16x32_f16(af, bf, ac, 0, 0, 0);
    }
    float bc = bcls[n16];
#pragma unroll
    for (int r = 0; r < 4; ++r)
        out[((size_t)(quad * 4 + r) * TT + s) * NB + n16] = ac[r] + bc;
}

extern "C" void kernel_launch(void* const* d_in, const int* in_sizes, int n_in,
                              void* d_out, int out_size, void* d_ws, size_t ws_size,
                              hipStream_t stream) {
    const float* x    = (const float*)d_in[0];
    const float* w1   = (const float*)d_in[1];
    const float* b1   = (const float*)d_in[2];
    const float* g1   = (const float*)d_in[3];
    const float* bt1  = (const float*)d_in[4];
    const float* m1   = (const float*)d_in[5];
    const float* v1   = (const float*)d_in[6];
    const float* w2   = (const float*)d_in[7];
    const float* b2   = (const float*)d_in[8];
    const float* g2   = (const float*)d_in[9];
    const float* bt2  = (const float*)d_in[10];
    const float* m2   = (const float*)d_in[11];
    const float* v2   = (const float*)d_in[12];
    const float* w3   = (const float*)d_in[13];
    const float* b3   = (const float*)d_in[14];
    const float* g3   = (const float*)d_in[15];
    const float* bt3  = (const float*)d_in[16];
    const float* m3   = (const float*)d_in[17];
    const float* v3   = (const float*)d_in[18];
    const float* wih  = (const float*)d_in[19];
    const float* whh  = (const float*)d_in[20];
    const float* bih  = (const float*)d_in[21];
    const float* bhh  = (const float*)d_in[22];
    const float* wcls = (const float*)d_in[23];
    const float* bcls = (const float*)d_in[24];

    float* ws    = (float*)d_ws;
    f16*   out1h = (f16*)(ws + O_OUT1);
    f16*   out2h = (f16*)(ws + O_OUT2);
    f16*   out3h = (f16*)(ws + O_OUT3);
    f16*   gi2   = (f16*)(ws + O_GI);      // aliases out1h (dead after conv2)
    f16*   w2p   = (f16*)(ws + O_W2P);
    f16*   w3p   = (f16*)(ws + O_W3P);
    f16*   wclsp = (f16*)(ws + O_W3P) + 983040;
    f16*   wihp  = (f16*)(ws + O_WIHP);
    f16*   whhp  = (f16*)(ws + O_WHHP);    // dedicated region now
    f16*   hsave = (f16*)(ws + O_OUT3);    // aliases out3h (dead after gi_mfma)
    float* fout  = (float*)d_out;

    // all weight prep in ONE kernel
    pack_all_kernel<<<1473, 256, 0, stream>>>(w2, w3, wih, whh, wcls,
                                              w2p, w3p, wihp, whhp, wclsp);

    // conv stack (all f16 intermediates)
    conv1_kernel<<<dim3(512, 16), 256, 0, stream>>>(x, w1, b1, g1, bt1, m1, v1, out1h);
    conv2_mfma_kernel<<<dim3(64, 16), 256, 0, stream>>>(out1h, w2p, b2, g2, bt2, m2, v2, out2h);
    conv3_mfma_kernel<<<dim3(32, 16), 256, 0, stream>>>(out2h, w3p, b3, g3, bt3, m3, v3, out3h);

    // input-to-hidden GEMM via MFMA -> gi2 [s][g][b] fp16 (out1 region)
    gi_mfma_kernel<<<512, 256, 0, stream>>>(out3h, wihp, bih, gi2);

    // GRU scan: one block, pinned weights, h history -> hsave
    gru_mfma_kernel<<<1, 1024, 0, stream>>>(gi2, whhp, bhh, hsave);

    // classifier over the full h history (parallel, MFMA)
    cls_kernel<<<128, 256, 0, stream>>>(hsave, wclsp, bcls, fout);
}

// Round 10
// 1641.790 us; speedup vs baseline: 1.9175x; 1.9175x over previous
//
#include <hip/hip_runtime.h>
#include <hip/hip_bf16.h>
#include <math.h>

// Problem constants
#define BB 16
#define TT 512
#define FF 40
#define CC 256
#define HH 256
#define GG 768   // 3*H
#define NB 16

typedef _Float16 f16;
typedef __attribute__((ext_vector_type(8))) _Float16 f16x8;
typedef __attribute__((ext_vector_type(4))) _Float16 f16x4;
typedef __attribute__((ext_vector_type(4))) float f32x4;

// Workspace layout (float offsets). All activations f16.
#define O_OUT1 0u                       // out1h [b][h][w8][ci] f16 (33.5 MB); gi2 aliases after conv2
#define O_GI   0u                       // gi2 [s][g][b] f16, 12 MB
#define O_OUT2 16777216u                // out2h [b][h][w2][ci] f16 (8.4 MB)
#define O_OUT3 20971520u                // out3h [bt][c] f16 (4.2 MB); hsave aliases after gi_mfma
#define O_W2P  23068672u                // packed fp16 conv2 weights, 1638400 halves
#define O_W3P  24707072u                // packed fp16 conv3 weights, 983040 halves (+ wclsp 4096 halves)
#define O_WIHP 26345472u                // packed fp16 wih, 196608 halves
#define O_WHHP 26443776u                // packed fp16 whh, 196608 halves
// total 26542080 floats = 106.2 MB

__device__ __forceinline__ float sigm_fast(float x) {
    return __builtin_amdgcn_rcpf(1.f + __expf(-x));
}
__device__ __forceinline__ float tanh_fast(float x) {
    return 1.f - 2.f * __builtin_amdgcn_rcpf(1.f + __expf(2.f * x));
}

// ---------------- merged weight prep (proven in R9: part of the 0.563 ms side) ----------------
__device__ __forceinline__ void pack768(const float* __restrict__ src, f16* __restrict__ dst, int e) {
    int lane = e & 63;
    int r1 = e >> 6;                            // 0..383
    int tile = r1 % 48, kf = r1 / 48;
    int g = tile * 16 + (lane & 15);
    int k0 = kf * 32 + (lane >> 4) * 8;
    f16x8 v;
#pragma unroll
    for (int j = 0; j < 8; ++j)
        v[j] = (f16)src[(size_t)g * HH + k0 + j];
    *(f16x8*)(dst + (size_t)e * 8) = v;
}

__global__ __launch_bounds__(256) void pack_all_kernel(
    const float* __restrict__ w2, const float* __restrict__ w3,
    const float* __restrict__ wih, const float* __restrict__ whh,
    const float* __restrict__ wcls,
    f16* __restrict__ w2p, f16* __restrict__ w3p, f16* __restrict__ wihp,
    f16* __restrict__ whhp, f16* __restrict__ wclsp) {
    int blk = blockIdx.x;
    int tid = threadIdx.x;
    if (blk < 800) {                            // conv2 weights (25 taps)
        int e = blk * 256 + tid;
        int lane = e & 63;
        int r1 = e >> 6;
        int ntile = r1 & 15;
        int r2 = r1 >> 4;
        int cs4 = r2 & 3;
        int r3 = r2 >> 2;
        int cs = r3 & 1;
        int tap = r3 >> 1;
        int co = ntile * 16 + (lane & 15);
        int ci0 = cs * 128 + cs4 * 32 + (lane >> 4) * 8;
        f16x8 v;
#pragma unroll
        for (int j = 0; j < 8; ++j)
            v[j] = (f16)w2[(size_t)co * 6400 + (ci0 + j) * 25 + tap];
        *(f16x8*)(w2p + (size_t)e * 8) = v;
    } else if (blk < 1280) {                    // conv3 weights (15 taps, kw in {1,2,3})
        int e = (blk - 800) * 256 + tid;
        int lane = e & 63;
        int r1 = e >> 6;
        int ntile = r1 & 15;
        int r2 = r1 >> 4;
        int cs4 = r2 & 3;
        int r3 = r2 >> 2;
        int cs = r3 & 1;
        int tap = r3 >> 1;
        int kh = tap / 3, kw = tap % 3 + 1;
        int co = ntile * 16 + (lane & 15);
        int ci0 = cs * 128 + cs4 * 32 + (lane >> 4) * 8;
        f16x8 v;
#pragma unroll
        for (int j = 0; j < 8; ++j)
            v[j] = (f16)w3[(size_t)co * 6400 + (ci0 + j) * 25 + kh * 5 + kw];
        *(f16x8*)(w3p + (size_t)e * 8) = v;
    } else if (blk < 1376) {
        pack768(wih, wihp, (blk - 1280) * 256 + tid);
    } else if (blk < 1472) {
        pack768(whh, whhp, (blk - 1376) * 256 + tid);
    } else {                                    // wcls: 512 entries
#pragma unroll
        for (int i = 0; i < 2; ++i) {
            int e = tid + i * 256;
            int lane = e & 63, kf = e >> 6;
            int nb = lane & 15;
            int c0 = kf * 32 + (lane >> 4) * 8;
            f16x8 v;
#pragma unroll
            for (int j = 0; j < 8; ++j)
                v[j] = (f16)wcls[nb * HH + c0 + j];
            *(f16x8*)(wclsp + (size_t)e * 8) = v;
        }
    }
}

// ---------------- conv block 1 (fp32 compute, f16 output [b][h][w][ci]) ----------------
__global__ __launch_bounds__(256) void conv1_kernel(
    const float* __restrict__ x, const float* __restrict__ w1,
    const float* __restrict__ b1, const float* __restrict__ g1,
    const float* __restrict__ bt1, const float* __restrict__ m1,
    const float* __restrict__ v1, f16* __restrict__ out1h) {
    int h = blockIdx.x;          // 512
    int b = blockIdx.y;          // 16
    int c = threadIdx.x;         // 256
    __shared__ float xs[5][44];
    int t = threadIdx.x;
    if (t < 220) {
        int rr = t / 44, cc = t % 44;
        int hh = h + rr - 2, ww = cc - 2;
        float v = 0.f;
        if (hh >= 0 && hh < TT && ww >= 0 && ww < FF) v = x[(b * TT + hh) * FF + ww];
        xs[rr][cc] = v;
    }
    __syncthreads();
    float wr[25];
#pragma unroll
    for (int i = 0; i < 25; ++i) wr[i] = w1[c * 25 + i];
    float sc = g1[c] * rsqrtf(v1[c] + 1e-5f);
    float sh = (b1[c] - m1[c]) * sc + bt1[c];
    float conv[40];
#pragma unroll
    for (int w = 0; w < 40; ++w) conv[w] = 0.f;
#pragma unroll
    for (int kh = 0; kh < 5; ++kh) {
        float rr[44];
#pragma unroll
        for (int i = 0; i < 44; ++i) rr[i] = xs[kh][i];
#pragma unroll
        for (int kw = 0; kw < 5; ++kw) {
            float wv = wr[kh * 5 + kw];
#pragma unroll
            for (int w = 0; w < 40; ++w) conv[w] += rr[w + kw] * wv;
        }
    }
    f16* op = out1h + ((size_t)(b * TT + h) * 8) * CC + c;
#pragma unroll
    for (int j = 0; j < 8; ++j) {
        float m = 0.f;   // relu folded into pool
#pragma unroll
        for (int p = 0; p < 5; ++p) m = fmaxf(m, conv[j * 5 + p] * sc + sh);
        op[j * CC] = (f16)m;
    }
}

// ---------------- conv block 2: fp16 MFMA implicit GEMM (f16 in/out, proven) ----------------
__global__ __launch_bounds__(256) void conv2_mfma_kernel(
    const f16* __restrict__ in, const f16* __restrict__ w2p,
    const float* __restrict__ b2, const float* __restrict__ g2,
    const float* __restrict__ bt2, const float* __restrict__ m2,
    const float* __restrict__ v2, f16* __restrict__ out2h) {
    int htile = blockIdx.x;                 // 64
    int b = blockIdx.y;                     // 16
    int h0 = htile * 8;
    int t = threadIdx.x;
    int lane = t & 63, wid = t >> 6;
    int m16 = lane & 15, kq = lane >> 4;

    __shared__ f16 lds_a[12 * 12 * 136];    // 39168 B

#pragma unroll
    for (int i = 0; i < 39; ++i) {
        int idx = t + i * 256;
        if (idx < 9792) ((unsigned*)lds_a)[idx] = 0u;
    }
    __syncthreads();

    f32x4 acc[4][4];
#pragma unroll
    for (int mf = 0; mf < 4; ++mf)
#pragma unroll
        for (int nf = 0; nf < 4; ++nf) acc[mf][nf] = (f32x4)(0.f);

    for (int cs = 0; cs < 2; ++cs) {
        if (cs) __syncthreads();
        // stage: 12 rows x 8 w x 16 ci8-chunks = 1536 tasks of one 16-B copy
#pragma unroll
        for (int i = 0; i < 6; ++i) {
            int q = t + i * 256;
            int row = q >> 7, rem = q & 127;
            int w = rem >> 4, ci8 = (rem & 15) * 8;
            int hp = h0 - 2 + row;
            f16x8 v = (f16x8)((f16)0.f);
            if (hp >= 0 && hp < TT)
                v = *(const f16x8*)&in[((size_t)(b * TT + hp) * 8 + w) * CC + cs * 128 + ci8];
            *(f16x8*)&lds_a[row * 1632 + (w + 2) * 136 + ci8] = v;
        }
        __syncthreads();
        for (int kh = 0; kh < 5; ++kh) {
#pragma unroll
            for (int kw = 0; kw < 5; ++kw) {
                int tap = kh * 5 + kw;
#pragma unroll
                for (int cs4 = 0; cs4 < 4; ++cs4) {
                    f16x8 af[4];
#pragma unroll
                    for (int mf = 0; mf < 4; ++mf) {
                        int m = mf * 16 + m16;
                        int row = (m >> 3) + kh;
                        int wp = (m & 7) + kw;
                        af[mf] = *(const f16x8*)&lds_a[row * 1632 + wp * 136 + cs4 * 32 + kq * 8];
                    }
                    const f16x8* bp = (const f16x8*)w2p
                        + ((size_t)(((tap * 2 + cs) * 4 + cs4) * 16 + wid * 4) * 64 + lane);
#pragma unroll
                    for (int nf = 0; nf < 4; ++nf) {
                        f16x8 bf = bp[nf * 64];
#pragma unroll
                        for (int mf = 0; mf < 4; ++mf)
                            acc[mf][nf] = __builtin_amdgcn_mfma_f32_16x16x32_f16(af[mf], bf, acc[mf][nf], 0, 0, 0);
                    }
                }
            }
        }
    }

#pragma unroll
    for (int nf = 0; nf < 4; ++nf) {
        int co = wid * 64 + nf * 16 + m16;
        float sc = g2[co] * rsqrtf(v2[co] + 1e-5f);
        float sh = (b2[co] - m2[co]) * sc + bt2[co];
#pragma unroll
        for (int mf = 0; mf < 4; ++mf) {
            f32x4 v = acc[mf][nf];
            float p = 0.f;
            p = fmaxf(p, v[0] * sc + sh);
            p = fmaxf(p, v[1] * sc + sh);
            p = fmaxf(p, v[2] * sc + sh);
            p = fmaxf(p, v[3] * sc + sh);
            int dh = mf * 2 + (kq >> 1);
            int wout = kq & 1;
            out2h[((size_t)(b * TT + h0 + dh) * 2 + wout) * CC + co] = (f16)p;
        }
    }
}

// ---------------- conv block 3: fp16 MFMA implicit GEMM (f16 in/out, proven) ----------------
__global__ __launch_bounds__(256) void conv3_mfma_kernel(
    const f16* __restrict__ in, const f16* __restrict__ w3p,
    const float* __restrict__ b3, const float* __restrict__ g3,
    const float* __restrict__ bt3, const float* __restrict__ m3,
    const float* __restrict__ v3, f16* __restrict__ out3h) {
    int htile = blockIdx.x;                 // 32
    int b = blockIdx.y;                     // 16
    int h0 = htile * 16;
    int t = threadIdx.x;
    int lane = t & 63, wid = t >> 6;
    int m16 = lane & 15, quad = lane >> 4;
    int rb = m16 >> 1, wv = m16 & 1;

    __shared__ f16 lds_a[20 * 6 * 136];     // 32640 B

    for (int i = t; i < 8160; i += 256) ((unsigned*)lds_a)[i] = 0u;
    __syncthreads();

    f32x4 acc[2][4];
#pragma unroll
    for (int mf = 0; mf < 2; ++mf)
#pragma unroll
        for (int nf = 0; nf < 4; ++nf) acc[mf][nf] = (f32x4)(0.f);

    for (int cs = 0; cs < 2; ++cs) {
        if (cs) __syncthreads();
#pragma unroll
        for (int i = 0; i < 3; ++i) {
            int q = t + i * 256;
            if (q < 640) {
                int row = q >> 5, rem = q & 31;
                int w = rem >> 4, ci8 = (rem & 15) * 8;
                int hp = h0 - 2 + row;
                f16x8 v = (f16x8)((f16)0.f);
                if (hp >= 0 && hp < TT)
                    v = *(const f16x8*)&in[((size_t)(b * TT + hp) * 2 + w) * CC + cs * 128 + ci8];
                *(f16x8*)&lds_a[row * 816 + (w + 2) * 136 + ci8] = v;
            }
        }
        __syncthreads();
        for (int kh = 0; kh < 5; ++kh) {
#pragma unroll
            for (int kw3 = 0; kw3 < 3; ++kw3) {
                int tap = kh * 3 + kw3;
#pragma unroll
                for (int cs4 = 0; cs4 < 4; ++cs4) {
                    f16x8 af[2];
#pragma unroll
                    for (int mf = 0; mf < 2; ++mf) {
                        int row = mf * 8 + rb + kh;
                        int wp = wv + kw3 + 1;
                        af[mf] = *(const f16x8*)&lds_a[row * 816 + wp * 136 + cs4 * 32 + quad * 8];
                    }
                    const f16x8* bp = (const f16x8*)w3p
                        + ((size_t)(((tap * 2 + cs) * 4 + cs4) * 16 + wid * 4) * 64 + lane);
#pragma unroll
                    for (int nf = 0; nf < 4; ++nf) {
                        f16x8 bf = bp[nf * 64];
#pragma unroll
                        for (int mf = 0; mf < 2; ++mf)
                            acc[mf][nf] = __builtin_amdgcn_mfma_f32_16x16x32_f16(af[mf], bf, acc[mf][nf], 0, 0, 0);
                    }
                }
            }
        }
    }

#pragma unroll
    for (int nf = 0; nf < 4; ++nf) {
        int co = wid * 64 + nf * 16 + m16;
        float sc = g3[co] * rsqrtf(v3[co] + 1e-5f);
        float sh = (b3[co] - m3[co]) * sc + bt3[co];
#pragma unroll
        for (int mf = 0; mf < 2; ++mf) {
            f32x4 v = acc[mf][nf];
            float p0 = fmaxf(0.f, fmaxf(v[0], v[1]) * sc + sh);
            p0 = fmaxf(p0, fmaxf(0.f, fminf(v[0], v[1]) * sc + sh));
            float p1 = fmaxf(0.f, fmaxf(v[2], v[3]) * sc + sh);
            p1 = fmaxf(p1, fmaxf(0.f, fminf(v[2], v[3]) * sc + sh));
            int h = h0 + mf * 8 + quad * 2;
            out3h[((size_t)(b * TT + h)) * CC + co] = (f16)p0;
            out3h[((size_t)(b * TT + h + 1)) * CC + co] = (f16)p1;
        }
    }
}

// ---------------- gi GEMM via MFMA -> gi2 [s][g][b] fp16 (proven) ----------------
__global__ __launch_bounds__(256) void gi_mfma_kernel(
    const f16* __restrict__ feats, const f16* __restrict__ wihp,
    const float* __restrict__ bih, f16* __restrict__ gi2) {
    int bt0 = blockIdx.x * 16;
    int b0 = bt0 >> 9, s0 = bt0 & 511;
    int t = threadIdx.x;
    int w = t >> 6, lane = t & 63;
    int m16 = lane & 15, quad = lane >> 4;
    f32x4 acc[12];
#pragma unroll
    for (int i = 0; i < 12; ++i) acc[i] = (f32x4)(0.f);
#pragma unroll
    for (int kf = 0; kf < 8; ++kf) {
        f16x8 af = *(const f16x8*)&feats[((size_t)(bt0 + m16)) * CC + kf * 32 + quad * 8];
#pragma unroll
        for (int nt = 0; nt < 12; ++nt) {
            f16x8 bf = ((const f16x8*)wihp)[(size_t)(kf * 48 + w * 12 + nt) * 64 + lane];
            acc[nt] = __builtin_amdgcn_mfma_f32_16x16x32_f16(af, bf, acc[nt], 0, 0, 0);
        }
    }
#pragma unroll
    for (int nt = 0; nt < 12; ++nt) {
        int g = (w * 12 + nt) * 16 + m16;
        float bv = bih[g];
#pragma unroll
        for (int r = 0; r < 4; ++r) {
            int s = s0 + quad * 4 + r;
            gi2[((size_t)s * GG + g) * 16 + b0] = (f16)(acc[nt][r] + bv);
        }
    }
}

// ---------------- GRU scan: EXACT R8 version (HW-proven 1.082 ms) ----------------
// 1024 threads = 16 waves (4/SIMD). Wave w owns gate cols w*16..w*16+15: 3 pinned
// B-tiles (r,z,n) = 96 regs. hA double-buffered -> ONE barrier/step. gi read as
// 3 coalesced 8-B global loads/thread at top of step s. hsave stores deferred one
// step (scalar). R9's bundled edits (cross-step gi reg prefetch, 6-chain split,
// cooperative hsave copy) regressed 2.4x -- reverted wholesale.
__global__ __launch_bounds__(1024) void gru_mfma_kernel(
    const f16* __restrict__ gi2, const f16* __restrict__ whhp,
    const float* __restrict__ bhh, f16* __restrict__ hsave) {
    int t = threadIdx.x;
    int w = t >> 6, lane = t & 63;        // w = 0..15
    int n16 = lane & 15, quad = lane >> 4;
    __shared__ f16 hA[2][16 * 264];       // [parity][b][k], pad 8 halves

    for (int i = t; i < 2 * 16 * 264; i += 1024) ((f16*)hA)[i] = (f16)0.f;

    // preload + PIN 3 weight tiles (96 regs, lands in unified VGPR/AGPR file)
    f16x8 wfrag[8][3];
#pragma unroll
    for (int kf = 0; kf < 8; ++kf)
#pragma unroll
        for (int g = 0; g < 3; ++g)
            wfrag[kf][g] = ((const f16x8*)whhp)[(size_t)(kf * 48 + g * 16 + w) * 64 + lane];
#pragma unroll
    for (int kf = 0; kf < 8; ++kf)
#pragma unroll
        for (int g = 0; g < 3; ++g)
            asm volatile("" : "+v"(wfrag[kf][g]));   // opaque: cannot be re-loaded

    int c = w * 16 + n16;
    float bh0 = bhh[c], bh1 = bhh[HH + c], bh2 = bhh[2 * HH + c];
    float hold[4] = {0.f, 0.f, 0.f, 0.f};
    f16 hprev[4];
    __syncthreads();

    for (int s = 0; s < TT; ++s) {
        // gi loads for this step (drained before gate math)
        f16x4 gic[3];
#pragma unroll
        for (int j = 0; j < 3; ++j)
            gic[j] = *(const f16x4*)&gi2[((size_t)s * GG + c + j * HH) * 16 + quad * 4];

        // deferred hsave store for step s-1 (full step of drain slack)
        if (s > 0) {
#pragma unroll
            for (int r = 0; r < 4; ++r)
                hsave[((size_t)(s - 1) * 16 + (quad * 4 + r)) * HH + c] = hprev[r];
        }

        f32x4 acc[3];
#pragma unroll
        for (int g = 0; g < 3; ++g) acc[g] = (f32x4)(0.f);
#pragma unroll
        for (int kf = 0; kf < 8; ++kf) {
            f16x8 af = *(const f16x8*)&hA[s & 1][n16 * 264 + kf * 32 + quad * 8];
#pragma unroll
            for (int g = 0; g < 3; ++g)
                acc[g] = __builtin_amdgcn_mfma_f32_16x16x32_f16(af, wfrag[kf][g], acc[g], 0, 0, 0);
        }

#pragma unroll
        for (int r = 0; r < 4; ++r) {
            float rr = sigm_fast((float)gic[0][r] + bh0 + acc[0][r]);
            float zz = sigm_fast((float)gic[1][r] + bh1 + acc[1][r]);
            float nn = tanh_fast((float)gic[2][r] + rr * (bh2 + acc[2][r]));
            hold[r] = nn + zz * (hold[r] - nn);
        }

        int nb = (s + 1) & 1;
#pragma unroll
        for (int r = 0; r < 4; ++r) {
            f16 hv = (f16)hold[r];
            hprev[r] = hv;
            hA[nb][(quad * 4 + r) * 264 + c] = hv;
        }
        __syncthreads();                  // writes(s) visible; all reads(s) done
    }
    // final hsave store (step TT-1)
#pragma unroll
    for (int r = 0; r < 4; ++r)
        hsave[((size_t)(TT - 1) * 16 + (quad * 4 + r)) * HH + c] = hprev[r];
}

// ---------------- classifier: [8192 bt x 256] @ [256 x 16], MFMA (proven) ----------------
__global__ __launch_bounds__(256) void cls_kernel(
    const f16* __restrict__ hsave, const f16* __restrict__ wclsp,
    const float* __restrict__ bcls, float* __restrict__ out) {
    int s = blockIdx.x * 4 + (threadIdx.x >> 6);   // grid 128, one s per wave
    int lane = threadIdx.x & 63;
    int n16 = lane & 15, quad = lane >> 4;
    f32x4 ac = (f32x4)(0.f);
#pragma unroll
    for (int kf = 0; kf < 8; ++kf) {
        f16x8 af = *(const f16x8*)&hsave[((size_t)s * 16 + n16) * 256 + kf * 32 + quad * 8];
        f16x8 bf = ((const f16x8*)wclsp)[kf * 64 + lane];
        ac = __builtin_amdgcn_mfma_f32_16x16x32_f16(af, bf, ac, 0, 0, 0);
    }
    float bc = bcls[n16];
#pragma unroll
    for (int r = 0; r < 4; ++r)
        out[((size_t)(quad * 4 + r) * TT + s) * NB + n16] = ac[r] + bc;
}

extern "C" void kernel_launch(void* const* d_in, const int* in_sizes, int n_in,
                              void* d_out, int out_size, void* d_ws, size_t ws_size,
                              hipStream_t stream) {
    const float* x    = (const float*)d_in[0];
    const float* w1   = (const float*)d_in[1];
    const float* b1   = (const float*)d_in[2];
    const float* g1   = (const float*)d_in[3];
    const float* bt1  = (const float*)d_in[4];
    const float* m1   = (const float*)d_in[5];
    const float* v1   = (const float*)d_in[6];
    const float* w2   = (const float*)d_in[7];
    const float* b2   = (const float*)d_in[8];
    const float* g2   = (const float*)d_in[9];
    const float* bt2  = (const float*)d_in[10];
    const float* m2   = (const float*)d_in[11];
    const float* v2   = (const float*)d_in[12];
    const float* w3   = (const float*)d_in[13];
    const float* b3   = (const float*)d_in[14];
    const float* g3   = (const float*)d_in[15];
    const float* bt3  = (const float*)d_in[16];
    const float* m3   = (const float*)d_in[17];
    const float* v3   = (const float*)d_in[18];
    const float* wih  = (const float*)d_in[19];
    const float* whh  = (const float*)d_in[20];
    const float* bih  = (const float*)d_in[21];
    const float* bhh  = (const float*)d_in[22];
    const float* wcls = (const float*)d_in[23];
    const float* bcls = (const float*)d_in[24];

    float* ws    = (float*)d_ws;
    f16*   out1h = (f16*)(ws + O_OUT1);
    f16*   out2h = (f16*)(ws + O_OUT2);
    f16*   out3h = (f16*)(ws + O_OUT3);
    f16*   gi2   = (f16*)(ws + O_GI);      // aliases out1h (dead after conv2)
    f16*   w2p   = (f16*)(ws + O_W2P);
    f16*   w3p   = (f16*)(ws + O_W3P);
    f16*   wclsp = (f16*)(ws + O_W3P) + 983040;
    f16*   wihp  = (f16*)(ws + O_WIHP);
    f16*   whhp  = (f16*)(ws + O_WHHP);
    f16*   hsave = (f16*)(ws + O_OUT3);    // aliases out3h (dead after gi_mfma)
    float* fout  = (float*)d_out;

    // all weight prep in ONE kernel
    pack_all_kernel<<<1473, 256, 0, stream>>>(w2, w3, wih, whh, wcls,
                                              w2p, w3p, wihp, whhp, wclsp);

    // conv stack (all f16 intermediates)
    conv1_kernel<<<dim3(512, 16), 256, 0, stream>>>(x, w1, b1, g1, bt1, m1, v1, out1h);
    conv2_mfma_kernel<<<dim3(64, 16), 256, 0, stream>>>(out1h, w2p, b2, g2, bt2, m2, v2, out2h);
    conv3_mfma_kernel<<<dim3(32, 16), 256, 0, stream>>>(out2h, w3p, b3, g3, bt3, m3, v3, out3h);

    // input-to-hidden GEMM via MFMA -> gi2 [s][g][b] fp16 (out1 region)
    gi_mfma_kernel<<<512, 256, 0, stream>>>(out3h, wihp, bih, gi2);

    // GRU scan: one block, pinned weights, h history -> hsave
    gru_mfma_kernel<<<1, 1024, 0, stream>>>(gi2, whhp, bhh, hsave);

    // classifier over the full h history (parallel, MFMA)
    cls_kernel<<<128, 256, 0, stream>>>(hsave, wclsp, bcls, fout);
}

// Round 11
// 1609.040 us; speedup vs baseline: 1.9565x; 1.0204x over previous
//
#include <hip/hip_runtime.h>
#include <hip/hip_bf16.h>
#include <math.h>

// Problem constants
#define BB 16
#define TT 512
#define FF 40
#define CC 256
#define HH 256
#define GG 768   // 3*H
#define NB 16

typedef _Float16 f16;
typedef __attribute__((ext_vector_type(8))) _Float16 f16x8;
typedef __attribute__((ext_vector_type(4))) _Float16 f16x4;
typedef __attribute__((ext_vector_type(4))) float f32x4;

// Workspace layout (float offsets). All activations f16.
#define O_OUT1 0u                       // out1h [b][h][w8][ci] f16 (33.5 MB); gi2 aliases after conv2
#define O_GI   0u                       // gi2 [s][g][b] f16, 12 MB
#define O_OUT2 16777216u                // out2h [b][h][w2][ci] f16 (8.4 MB)
#define O_OUT3 20971520u                // hsave f16 [s][b][c] (feats no longer materialized)
#define O_W2P  23068672u                // packed fp16 conv2 weights, 1638400 halves
#define O_W3P  24707072u                // packed fp16 conv3 weights, 983040 halves (+ wclsp 4096 halves)
#define O_WIHP 26345472u                // packed fp16 wih, 196608 halves
#define O_WHHP 26443776u                // packed fp16 whh, 196608 halves
// total 26542080 floats = 106.2 MB

__device__ __forceinline__ float sigm_fast(float x) {
    return __builtin_amdgcn_rcpf(1.f + __expf(-x));
}
__device__ __forceinline__ float tanh_fast(float x) {
    return 1.f - 2.f * __builtin_amdgcn_rcpf(1.f + __expf(2.f * x));
}

// ---------------- merged weight prep (proven) ----------------
__device__ __forceinline__ void pack768(const float* __restrict__ src, f16* __restrict__ dst, int e) {
    int lane = e & 63;
    int r1 = e >> 6;                            // 0..383
    int tile = r1 % 48, kf = r1 / 48;
    int g = tile * 16 + (lane & 15);
    int k0 = kf * 32 + (lane >> 4) * 8;
    f16x8 v;
#pragma unroll
    for (int j = 0; j < 8; ++j)
        v[j] = (f16)src[(size_t)g * HH + k0 + j];
    *(f16x8*)(dst + (size_t)e * 8) = v;
}

__global__ __launch_bounds__(256) void pack_all_kernel(
    const float* __restrict__ w2, const float* __restrict__ w3,
    const float* __restrict__ wih, const float* __restrict__ whh,
    const float* __restrict__ wcls,
    f16* __restrict__ w2p, f16* __restrict__ w3p, f16* __restrict__ wihp,
    f16* __restrict__ whhp, f16* __restrict__ wclsp) {
    int blk = blockIdx.x;
    int tid = threadIdx.x;
    if (blk < 800) {                            // conv2 weights (25 taps)
        int e = blk * 256 + tid;
        int lane = e & 63;
        int r1 = e >> 6;
        int ntile = r1 & 15;
        int r2 = r1 >> 4;
        int cs4 = r2 & 3;
        int r3 = r2 >> 2;
        int cs = r3 & 1;
        int tap = r3 >> 1;
        int co = ntile * 16 + (lane & 15);
        int ci0 = cs * 128 + cs4 * 32 + (lane >> 4) * 8;
        f16x8 v;
#pragma unroll
        for (int j = 0; j < 8; ++j)
            v[j] = (f16)w2[(size_t)co * 6400 + (ci0 + j) * 25 + tap];
        *(f16x8*)(w2p + (size_t)e * 8) = v;
    } else if (blk < 1280) {                    // conv3 weights (15 taps, kw in {1,2,3})
        int e = (blk - 800) * 256 + tid;
        int lane = e & 63;
        int r1 = e >> 6;
        int ntile = r1 & 15;
        int r2 = r1 >> 4;
        int cs4 = r2 & 3;
        int r3 = r2 >> 2;
        int cs = r3 & 1;
        int tap = r3 >> 1;
        int kh = tap / 3, kw = tap % 3 + 1;
        int co = ntile * 16 + (lane & 15);
        int ci0 = cs * 128 + cs4 * 32 + (lane >> 4) * 8;
        f16x8 v;
#pragma unroll
        for (int j = 0; j < 8; ++j)
            v[j] = (f16)w3[(size_t)co * 6400 + (ci0 + j) * 25 + kh * 5 + kw];
        *(f16x8*)(w3p + (size_t)e * 8) = v;
    } else if (blk < 1376) {
        pack768(wih, wihp, (blk - 1280) * 256 + tid);
    } else if (blk < 1472) {
        pack768(whh, whhp, (blk - 1376) * 256 + tid);
    } else {                                    // wcls: 512 entries
#pragma unroll
        for (int i = 0; i < 2; ++i) {
            int e = tid + i * 256;
            int lane = e & 63, kf = e >> 6;
            int nb = lane & 15;
            int c0 = kf * 32 + (lane >> 4) * 8;
            f16x8 v;
#pragma unroll
            for (int j = 0; j < 8; ++j)
                v[j] = (f16)wcls[nb * HH + c0 + j];
            *(f16x8*)(wclsp + (size_t)e * 8) = v;
        }
    }
}

// ---------------- conv block 1 (fp32 compute, f16 output [b][h][w][ci]) ----------------
__global__ __launch_bounds__(256) void conv1_kernel(
    const float* __restrict__ x, const float* __restrict__ w1,
    const float* __restrict__ b1, const float* __restrict__ g1,
    const float* __restrict__ bt1, const float* __restrict__ m1,
    const float* __restrict__ v1, f16* __restrict__ out1h) {
    int h = blockIdx.x;          // 512
    int b = blockIdx.y;          // 16
    int c = threadIdx.x;         // 256
    __shared__ float xs[5][44];
    int t = threadIdx.x;
    if (t < 220) {
        int rr = t / 44, cc = t % 44;
        int hh = h + rr - 2, ww = cc - 2;
        float v = 0.f;
        if (hh >= 0 && hh < TT && ww >= 0 && ww < FF) v = x[(b * TT + hh) * FF + ww];
        xs[rr][cc] = v;
    }
    __syncthreads();
    float wr[25];
#pragma unroll
    for (int i = 0; i < 25; ++i) wr[i] = w1[c * 25 + i];
    float sc = g1[c] * rsqrtf(v1[c] + 1e-5f);
    float sh = (b1[c] - m1[c]) * sc + bt1[c];
    float conv[40];
#pragma unroll
    for (int w = 0; w < 40; ++w) conv[w] = 0.f;
#pragma unroll
    for (int kh = 0; kh < 5; ++kh) {
        float rr[44];
#pragma unroll
        for (int i = 0; i < 44; ++i) rr[i] = xs[kh][i];
#pragma unroll
        for (int kw = 0; kw < 5; ++kw) {
            float wv = wr[kh * 5 + kw];
#pragma unroll
            for (int w = 0; w < 40; ++w) conv[w] += rr[w + kw] * wv;
        }
    }
    f16* op = out1h + ((size_t)(b * TT + h) * 8) * CC + c;
#pragma unroll
    for (int j = 0; j < 8; ++j) {
        float m = 0.f;   // relu folded into pool
#pragma unroll
        for (int p = 0; p < 5; ++p) m = fmaxf(m, conv[j * 5 + p] * sc + sh);
        op[j * CC] = (f16)m;
    }
}

// ---------------- conv block 2: fp16 MFMA implicit GEMM (f16 in/out, proven) ----------------
__global__ __launch_bounds__(256) void conv2_mfma_kernel(
    const f16* __restrict__ in, const f16* __restrict__ w2p,
    const float* __restrict__ b2, const float* __restrict__ g2,
    const float* __restrict__ bt2, const float* __restrict__ m2,
    const float* __restrict__ v2, f16* __restrict__ out2h) {
    int htile = blockIdx.x;                 // 64
    int b = blockIdx.y;                     // 16
    int h0 = htile * 8;
    int t = threadIdx.x;
    int lane = t & 63, wid = t >> 6;
    int m16 = lane & 15, kq = lane >> 4;

    __shared__ f16 lds_a[12 * 12 * 136];    // 39168 B

#pragma unroll
    for (int i = 0; i < 39; ++i) {
        int idx = t + i * 256;
        if (idx < 9792) ((unsigned*)lds_a)[idx] = 0u;
    }
    __syncthreads();

    f32x4 acc[4][4];
#pragma unroll
    for (int mf = 0; mf < 4; ++mf)
#pragma unroll
        for (int nf = 0; nf < 4; ++nf) acc[mf][nf] = (f32x4)(0.f);

    for (int cs = 0; cs < 2; ++cs) {
        if (cs) __syncthreads();
        // stage: 12 rows x 8 w x 16 ci8-chunks = 1536 tasks of one 16-B copy
#pragma unroll
        for (int i = 0; i < 6; ++i) {
            int q = t + i * 256;
            int row = q >> 7, rem = q & 127;
            int w = rem >> 4, ci8 = (rem & 15) * 8;
            int hp = h0 - 2 + row;
            f16x8 v = (f16x8)((f16)0.f);
            if (hp >= 0 && hp < TT)
                v = *(const f16x8*)&in[((size_t)(b * TT + hp) * 8 + w) * CC + cs * 128 + ci8];
            *(f16x8*)&lds_a[row * 1632 + (w + 2) * 136 + ci8] = v;
        }
        __syncthreads();
        for (int kh = 0; kh < 5; ++kh) {
#pragma unroll
            for (int kw = 0; kw < 5; ++kw) {
                int tap = kh * 5 + kw;
#pragma unroll
                for (int cs4 = 0; cs4 < 4; ++cs4) {
                    f16x8 af[4];
#pragma unroll
                    for (int mf = 0; mf < 4; ++mf) {
                        int m = mf * 16 + m16;
                        int row = (m >> 3) + kh;
                        int wp = (m & 7) + kw;
                        af[mf] = *(const f16x8*)&lds_a[row * 1632 + wp * 136 + cs4 * 32 + kq * 8];
                    }
                    const f16x8* bp = (const f16x8*)w2p
                        + ((size_t)(((tap * 2 + cs) * 4 + cs4) * 16 + wid * 4) * 64 + lane);
#pragma unroll
                    for (int nf = 0; nf < 4; ++nf) {
                        f16x8 bf = bp[nf * 64];
#pragma unroll
                        for (int mf = 0; mf < 4; ++mf)
                            acc[mf][nf] = __builtin_amdgcn_mfma_f32_16x16x32_f16(af[mf], bf, acc[mf][nf], 0, 0, 0);
                    }
                }
            }
        }
    }

#pragma unroll
    for (int nf = 0; nf < 4; ++nf) {
        int co = wid * 64 + nf * 16 + m16;
        float sc = g2[co] * rsqrtf(v2[co] + 1e-5f);
        float sh = (b2[co] - m2[co]) * sc + bt2[co];
#pragma unroll
        for (int mf = 0; mf < 4; ++mf) {
            f32x4 v = acc[mf][nf];
            float p = 0.f;
            p = fmaxf(p, v[0] * sc + sh);
            p = fmaxf(p, v[1] * sc + sh);
            p = fmaxf(p, v[2] * sc + sh);
            p = fmaxf(p, v[3] * sc + sh);
            int dh = mf * 2 + (kq >> 1);
            int wout = kq & 1;
            out2h[((size_t)(b * TT + h0 + dh) * 2 + wout) * CC + co] = (f16)p;
        }
    }
}

// ---------------- FUSED conv3 + gi: one block produces 16 feats rows AND their gi ----------------
// Phase 1 (conv3, proven math): M=32 (16h x 2w), N=256 co, K=15 taps x 256 ci;
// epilogue writes the 16x256 pooled feats tile to LDS instead of global.
// Phase 2 (gi, proven math): [16 bt x 256 c] @ [256 c x 768 g] with A from LDS.
// Same block partitioning as the old separate kernels: bt = b*512 + htile*16 + m.
__global__ __launch_bounds__(256) void conv3gi_kernel(
    const f16* __restrict__ in, const f16* __restrict__ w3p,
    const float* __restrict__ b3, const float* __restrict__ g3,
    const float* __restrict__ bt3, const float* __restrict__ m3,
    const float* __restrict__ v3, const f16* __restrict__ wihp,
    const float* __restrict__ bih, f16* __restrict__ gi2) {
    int htile = blockIdx.x;                 // 32
    int b = blockIdx.y;                     // 16
    int h0 = htile * 16;
    int t = threadIdx.x;
    int lane = t & 63, wid = t >> 6;
    int m16 = lane & 15, quad = lane >> 4;
    int rb = m16 >> 1, wv = m16 & 1;

    __shared__ f16 lds_a[20 * 6 * 136];     // 32640 B
    __shared__ f16 feats_s[16 * 264];       // 8448 B: pooled feats tile [m][c]

    for (int i = t; i < 8160; i += 256) ((unsigned*)lds_a)[i] = 0u;
    __syncthreads();

    f32x4 acc[2][4];
#pragma unroll
    for (int mf = 0; mf < 2; ++mf)
#pragma unroll
        for (int nf = 0; nf < 4; ++nf) acc[mf][nf] = (f32x4)(0.f);

    for (int cs = 0; cs < 2; ++cs) {
        if (cs) __syncthreads();
#pragma unroll
        for (int i = 0; i < 3; ++i) {
            int q = t + i * 256;
            if (q < 640) {
                int row = q >> 5, rem = q & 31;
                int w = rem >> 4, ci8 = (rem & 15) * 8;
                int hp = h0 - 2 + row;
                f16x8 v = (f16x8)((f16)0.f);
                if (hp >= 0 && hp < TT)
                    v = *(const f16x8*)&in[((size_t)(b * TT + hp) * 2 + w) * CC + cs * 128 + ci8];
                *(f16x8*)&lds_a[row * 816 + (w + 2) * 136 + ci8] = v;
            }
        }
        __syncthreads();
        for (int kh = 0; kh < 5; ++kh) {
#pragma unroll
            for (int kw3 = 0; kw3 < 3; ++kw3) {
                int tap = kh * 3 + kw3;
#pragma unroll
                for (int cs4 = 0; cs4 < 4; ++cs4) {
                    f16x8 af[2];
#pragma unroll
                    for (int mf = 0; mf < 2; ++mf) {
                        int row = mf * 8 + rb + kh;
                        int wp = wv + kw3 + 1;
                        af[mf] = *(const f16x8*)&lds_a[row * 816 + wp * 136 + cs4 * 32 + quad * 8];
                    }
                    const f16x8* bp = (const f16x8*)w3p
                        + ((size_t)(((tap * 2 + cs) * 4 + cs4) * 16 + wid * 4) * 64 + lane);
#pragma unroll
                    for (int nf = 0; nf < 4; ++nf) {
                        f16x8 bf = bp[nf * 64];
#pragma unroll
                        for (int mf = 0; mf < 2; ++mf)
                            acc[mf][nf] = __builtin_amdgcn_mfma_f32_16x16x32_f16(af[mf], bf, acc[mf][nf], 0, 0, 0);
                    }
                }
            }
        }
    }

    // conv3 epilogue -> feats tile in LDS (m = h - h0, c = co)
#pragma unroll
    for (int nf = 0; nf < 4; ++nf) {
        int co = wid * 64 + nf * 16 + m16;
        float sc = g3[co] * rsqrtf(v3[co] + 1e-5f);
        float sh = (b3[co] - m3[co]) * sc + bt3[co];
#pragma unroll
        for (int mf = 0; mf < 2; ++mf) {
            f32x4 v = acc[mf][nf];
            float p0 = fmaxf(0.f, fmaxf(v[0], v[1]) * sc + sh);
            p0 = fmaxf(p0, fmaxf(0.f, fminf(v[0], v[1]) * sc + sh));
            float p1 = fmaxf(0.f, fmaxf(v[2], v[3]) * sc + sh);
            p1 = fmaxf(p1, fmaxf(0.f, fminf(v[2], v[3]) * sc + sh));
            int m = mf * 8 + quad * 2;
            feats_s[m * 264 + co] = (f16)p0;
            feats_s[(m + 1) * 264 + co] = (f16)p1;
        }
    }
    __syncthreads();

    // gi phase: A from feats_s, B = wihp; wave wid covers 12 n-tiles
    f32x4 gacc[12];
#pragma unroll
    for (int i = 0; i < 12; ++i) gacc[i] = (f32x4)(0.f);
#pragma unroll
    for (int kf = 0; kf < 8; ++kf) {
        f16x8 af = *(const f16x8*)&feats_s[m16 * 264 + kf * 32 + quad * 8];
#pragma unroll
        for (int nt = 0; nt < 12; ++nt) {
            f16x8 bf = ((const f16x8*)wihp)[(size_t)(kf * 48 + wid * 12 + nt) * 64 + lane];
            gacc[nt] = __builtin_amdgcn_mfma_f32_16x16x32_f16(af, bf, gacc[nt], 0, 0, 0);
        }
    }
#pragma unroll
    for (int nt = 0; nt < 12; ++nt) {
        int g = (wid * 12 + nt) * 16 + m16;
        float bv = bih[g];
#pragma unroll
        for (int r = 0; r < 4; ++r) {
            int s = h0 + quad * 4 + r;          // s0 = htile*16
            gi2[((size_t)s * GG + g) * 16 + b] = (f16)(gacc[nt][r] + bv);
        }
    }
}

// ---------------- GRU scan: R8 structure + raw lgkm-only barrier ----------------
// Single change vs the proven 1.085 ms version: the in-loop __syncthreads (which
// compiles to s_waitcnt vmcnt(0) lgkmcnt(0) + s_barrier) is replaced by
// s_waitcnt lgkmcnt(0) + s_barrier. vmcnt drain is semantically unneeded here:
// hA ordering is LDS-only; gic loads are consumed via data-dependency waits;
// hsave stores are read only by the next kernel (ordered by kernel boundary).
__global__ __launch_bounds__(1024) void gru_mfma_kernel(
    const f16* __restrict__ gi2, const f16* __restrict__ whhp,
    const float* __restrict__ bhh, f16* __restrict__ hsave) {
    int t = threadIdx.x;
    int w = t >> 6, lane = t & 63;        // w = 0..15
    int n16 = lane & 15, quad = lane >> 4;
    __shared__ f16 hA[2][16 * 264];       // [parity][b][k], pad 8 halves

    for (int i = t; i < 2 * 16 * 264; i += 1024) ((f16*)hA)[i] = (f16)0.f;

    // preload + PIN 3 weight tiles (96 regs, lands in unified VGPR/AGPR file)
    f16x8 wfrag[8][3];
#pragma unroll
    for (int kf = 0; kf < 8; ++kf)
#pragma unroll
        for (int g = 0; g < 3; ++g)
            wfrag[kf][g] = ((const f16x8*)whhp)[(size_t)(kf * 48 + g * 16 + w) * 64 + lane];
#pragma unroll
    for (int kf = 0; kf < 8; ++kf)
#pragma unroll
        for (int g = 0; g < 3; ++g)
            asm volatile("" : "+v"(wfrag[kf][g]));   // opaque: cannot be re-loaded

    int c = w * 16 + n16;
    float bh0 = bhh[c], bh1 = bhh[HH + c], bh2 = bhh[2 * HH + c];
    float hold[4] = {0.f, 0.f, 0.f, 0.f};
    f16 hprev[4];
    __syncthreads();

    for (int s = 0; s < TT; ++s) {
        // gi loads for this step (drained before gate math by dependency waits)
        f16x4 gic[3];
#pragma unroll
        for (int j = 0; j < 3; ++j)
            gic[j] = *(const f16x4*)&gi2[((size_t)s * GG + c + j * HH) * 16 + quad * 4];

        // deferred hsave store for step s-1 (fire-and-forget)
        if (s > 0) {
#pragma unroll
            for (int r = 0; r < 4; ++r)
                hsave[((size_t)(s - 1) * 16 + (quad * 4 + r)) * HH + c] = hprev[r];
        }

        f32x4 acc[3];
#pragma unroll
        for (int g = 0; g < 3; ++g) acc[g] = (f32x4)(0.f);
#pragma unroll
        for (int kf = 0; kf < 8; ++kf) {
            f16x8 af = *(const f16x8*)&hA[s & 1][n16 * 264 + kf * 32 + quad * 8];
#pragma unroll
            for (int g = 0; g < 3; ++g)
                acc[g] = __builtin_amdgcn_mfma_f32_16x16x32_f16(af, wfrag[kf][g], acc[g], 0, 0, 0);
        }

#pragma unroll
        for (int r = 0; r < 4; ++r) {
            float rr = sigm_fast((float)gic[0][r] + bh0 + acc[0][r]);
            float zz = sigm_fast((float)gic[1][r] + bh1 + acc[1][r]);
            float nn = tanh_fast((float)gic[2][r] + rr * (bh2 + acc[2][r]));
            hold[r] = nn + zz * (hold[r] - nn);
        }

        int nb = (s + 1) & 1;
#pragma unroll
        for (int r = 0; r < 4; ++r) {
            f16 hv = (f16)hold[r];
            hprev[r] = hv;
            hA[nb][(quad * 4 + r) * 264 + c] = hv;
        }
        // raw barrier: LDS-only drain, no vmcnt(0)
        asm volatile("s_waitcnt lgkmcnt(0)\n\ts_barrier" ::: "memory");
    }
    // final hsave store (step TT-1)
#pragma unroll
    for (int r = 0; r < 4; ++r)
        hsave[((size_t)(TT - 1) * 16 + (quad * 4 + r)) * HH + c] = hprev[r];
}

// ---------------- classifier: [8192 bt x 256] @ [256 x 16], MFMA (proven) ----------------
__global__ __launch_bounds__(256) void cls_kernel(
    const f16* __restrict__ hsave, const f16* __restrict__ wclsp,
    const float* __restrict__ bcls, float* __restrict__ out) {
    int s = blockIdx.x * 4 + (threadIdx.x >> 6);   // grid 128, one s per wave
    int lane = threadIdx.x & 63;
    int n16 = lane & 15, quad = lane >> 4;
    f32x4 ac = (f32x4)(0.f);
#pragma unroll
    for (int kf = 0; kf < 8; ++kf) {
        f16x8 af = *(const f16x8*)&hsave[((size_t)s * 16 + n16) * 256 + kf * 32 + quad * 8];
        f16x8 bf = ((const f16x8*)wclsp)[kf * 64 + lane];
        ac = __builtin_amdgcn_mfma_f32_16x16x32_f16(af, bf, ac, 0, 0, 0);
    }
    float bc = bcls[n16];
#pragma unroll
    for (int r = 0; r < 4; ++r)
        out[((size_t)(quad * 4 + r) * TT + s) * NB + n16] = ac[r] + bc;
}

extern "C" void kernel_launch(void* const* d_in, const int* in_sizes, int n_in,
                              void* d_out, int out_size, void* d_ws, size_t ws_size,
                              hipStream_t stream) {
    const float* x    = (const float*)d_in[0];
    const float* w1   = (const float*)d_in[1];
    const float* b1   = (const float*)d_in[2];
    const float* g1   = (const float*)d_in[3];
    const float* bt1  = (const float*)d_in[4];
    const float* m1   = (const float*)d_in[5];
    const float* v1   = (const float*)d_in[6];
    const float* w2   = (const float*)d_in[7];
    const float* b2   = (const float*)d_in[8];
    const float* g2   = (const float*)d_in[9];
    const float* bt2  = (const float*)d_in[10];
    const float* m2   = (const float*)d_in[11];
    const float* v2   = (const float*)d_in[12];
    const float* w3   = (const float*)d_in[13];
    const float* b3   = (const float*)d_in[14];
    const float* g3   = (const float*)d_in[15];
    const float* bt3  = (const float*)d_in[16];
    const float* m3   = (const float*)d_in[17];
    const float* v3   = (const float*)d_in[18];
    const float* wih  = (const float*)d_in[19];
    const float* whh  = (const float*)d_in[20];
    const float* bih  = (const float*)d_in[21];
    const float* bhh  = (const float*)d_in[22];
    const float* wcls = (const float*)d_in[23];
    const float* bcls = (const float*)d_in[24];

    float* ws    = (float*)d_ws;
    f16*   out1h = (f16*)(ws + O_OUT1);
    f16*   out2h = (f16*)(ws + O_OUT2);
    f16*   gi2   = (f16*)(ws + O_GI);      // aliases out1h (dead after conv2)
    f16*   w2p   = (f16*)(ws + O_W2P);
    f16*   w3p   = (f16*)(ws + O_W3P);
    f16*   wclsp = (f16*)(ws + O_W3P) + 983040;
    f16*   wihp  = (f16*)(ws + O_WIHP);
    f16*   whhp  = (f16*)(ws + O_WHHP);
    f16*   hsave = (f16*)(ws + O_OUT3);
    float* fout  = (float*)d_out;

    // all weight prep in ONE kernel
    pack_all_kernel<<<1473, 256, 0, stream>>>(w2, w3, wih, whh, wcls,
                                              w2p, w3p, wihp, whhp, wclsp);

    // conv stack (all f16 intermediates)
    conv1_kernel<<<dim3(512, 16), 256, 0, stream>>>(x, w1, b1, g1, bt1, m1, v1, out1h);
    conv2_mfma_kernel<<<dim3(64, 16), 256, 0, stream>>>(out1h, w2p, b2, g2, bt2, m2, v2, out2h);

    // fused conv3 + gi: feats never materialized; writes gi2 [s][g][b] directly
    conv3gi_kernel<<<dim3(32, 16), 256, 0, stream>>>(out2h, w3p, b3, g3, bt3, m3, v3,
                                                     wihp, bih, gi2);

    // GRU scan: one block, pinned weights, h history -> hsave
    gru_mfma_kernel<<<1, 1024, 0, stream>>>(gi2, whhp, bhh, hsave);

    // classifier over the full h history (parallel, MFMA)
    cls_kernel<<<128, 256, 0, stream>>>(hsave, wclsp, bcls, fout);
}